// Round 12
// baseline (115.100 us; speedup 1.0000x reference)
//
#include <hip/hip_runtime.h>

#define HW        128
#define PLANE     16384            // 128*128
#define NCH       64
#define NB        32
#define NQ        4
#define NPART     8192             // per-quarter partial count
#define COUNT_INV (1.0f / 524288.0f)
#define EPSV      1e-5f

#define YELEMS    (NB * NCH * PLANE)            // 33,554,432
#define PART_OFF  (YELEMS / 2)                  // float index of partials in ws
#define WS_NEED   ((size_t)YELEMS * 2 + 16384 * 4)

typedef float    f4v __attribute__((ext_vector_type(4)));
typedef _Float16 h4v __attribute__((ext_vector_type(4)));
typedef _Float16 h8v __attribute__((ext_vector_type(8)));

// ws layout:
//   bytes [0 .. 67108863]           y as fp16 (NCHW, same indexing as x)
//   floats[PART_OFF .. +8191]       per-quarter sum,   idx = c*128 + (n*4+q)
//   floats[PART_OFF+8192 .. +16383] per-quarter sumsq, same layout

__device__ __forceinline__ void load_win(const float* __restrict__ bp, int r0, int w4,
                                         bool hasL, bool hasR, float (&v)[6][6]) {
#pragma unroll
    for (int i = 0; i < 6; ++i) {
        int g = r0 - 1 + i;
        if ((unsigned)g < (unsigned)HW) {
            const float* rp = bp + g * HW + w4;
            float4 m = *(const float4*)rp;
            v[i][0] = hasL ? rp[-1] : 0.f;
            v[i][1] = m.x; v[i][2] = m.y; v[i][3] = m.z; v[i][4] = m.w;
            v[i][5] = hasR ? rp[4] : 0.f;
        } else {
#pragma unroll
            for (int j = 0; j < 6; ++j) v[i][j] = 0.f;
        }
    }
}

__device__ __forceinline__ void conv_row(const float (&tp)[6], const float (&md)[6],
                                         const float (&bt)[6], const float* W,
                                         float bias, float (&acc)[4]) {
#pragma unroll
    for (int j = 0; j < 4; ++j) {
        float a = bias;
        a = fmaf(tp[j],     W[0], a);
        a = fmaf(tp[j + 1], W[1], a);
        a = fmaf(tp[j + 2], W[2], a);
        a = fmaf(md[j],     W[3], a);
        a = fmaf(md[j + 1], W[4], a);
        a = fmaf(md[j + 2], W[5], a);
        a = fmaf(bt[j],     W[6], a);
        a = fmaf(bt[j + 1], W[7], a);
        a = fmaf(bt[j + 2], W[8], a);
        acc[j] = a;
    }
}

// ---------- pass 1: conv -> y(fp16, L3-retained) + per-quarter sum/sumsq ----------
__global__ __launch_bounds__(256) void pass_conv_stats(const float* __restrict__ x,
                                                       const float* __restrict__ wgt,
                                                       const float* __restrict__ bias,
                                                       _Float16* __restrict__ yh,
                                                       float* __restrict__ partials) {
    __shared__ float red[8];
    const int bid   = blockIdx.x;        // plane*4 + q
    const int q     = bid & 3;
    const int plane = bid >> 2;          // n*64 + c
    const int c     = plane & 63;
    const int n     = plane >> 6;
    const int t     = threadIdx.x;
    const int cg    = t & 31, rg = t >> 5;
    const int w4    = cg * 4, r0 = q * 32 + rg * 4;
    const bool hasL = (cg != 0), hasR = (cg != 31);

    float W[9];
#pragma unroll
    for (int k = 0; k < 9; ++k) W[k] = wgt[c * 9 + k];
    const float bv = bias[c];
    const float* bp = x + (size_t)plane * PLANE;
    _Float16* yp = yh + (size_t)plane * PLANE;

    float v[6][6];
    load_win(bp, r0, w4, hasL, hasR, v);

    float sum = 0.f, sq = 0.f;
#pragma unroll
    for (int k = 0; k < 4; ++k) {
        float acc[4];
        conv_row(v[k], v[k + 1], v[k + 2], W, bv, acc);
        h4v hv;
        hv.x = (_Float16)acc[0]; hv.y = (_Float16)acc[1];
        hv.z = (_Float16)acc[2]; hv.w = (_Float16)acc[3];
        *(h4v*)(yp + (r0 + k) * HW + w4) = hv;   // normal store: keep in L3 for pass 2
#pragma unroll
        for (int j = 0; j < 4; ++j) {
            sum += acc[j];
            sq = fmaf(acc[j], acc[j], sq);
        }
    }

#pragma unroll
    for (int off = 32; off; off >>= 1) {
        sum += __shfl_down(sum, off);
        sq  += __shfl_down(sq, off);
    }
    const int wave = t >> 6, lane = t & 63;
    if (lane == 0) { red[wave] = sum; red[4 + wave] = sq; }
    __syncthreads();
    if (t == 0) {
        const int pi = n * 4 + q;        // 0..127
        partials[c * 128 + pi]         = red[0] + red[1] + red[2] + red[3];
        partials[NPART + c * 128 + pi] = red[4] + red[5] + red[6] + red[7];
    }
}

// ---------- pass 2: elementwise normalize + relu, 16 B/lane NT reads ----------
// 2048 blocks (one plane each) x 256 threads; thread owns 8 rows x 8 cols.
// 8 independent NT h8v loads issued before first use; stats fold hides under them.
__global__ __launch_bounds__(256) void pass_norm(const _Float16* __restrict__ yh,
                                                 const float* __restrict__ partials,
                                                 const float* __restrict__ gamma,
                                                 const float* __restrict__ beta,
                                                 float* __restrict__ out) {
    const int plane = blockIdx.x;        // n*64 + c
    const int c     = plane & 63;
    const int t     = threadIdx.x;
    const int cgrp  = t & 15, rgrp = t >> 4;
    const int col0  = cgrp * 8, row0 = rgrp * 8;

    const _Float16* yp = yh + (size_t)plane * PLANE;

    // issue all 8 row-loads up front (nontemporal: y is dead after this read)
    h8v hv[8];
#pragma unroll
    for (int r = 0; r < 8; ++r)
        hv[r] = __builtin_nontemporal_load((const h8v*)(yp + (row0 + r) * HW + col0));

    // stats fold: 128 partials per channel, coalesced, hidden under the loads
    const int lane = t & 63;
    float S = partials[c * 128 + lane]         + partials[c * 128 + 64 + lane];
    float Q = partials[NPART + c * 128 + lane] + partials[NPART + c * 128 + 64 + lane];
#pragma unroll
    for (int off = 32; off; off >>= 1) {
        S += __shfl_xor(S, off);
        Q += __shfl_xor(Q, off);
    }
    const float mean = S * COUNT_INV;
    const float var  = fmaxf(Q * COUNT_INV - mean * mean, 0.f);
    const float s    = gamma[c] * rsqrtf(var + EPSV);
    const float sh   = beta[c] - mean * s;

    float* op = out + (size_t)plane * PLANE;
#pragma unroll
    for (int r = 0; r < 8; ++r) {
        f4v o0, o1;
        o0.x = fmaxf(fmaf((float)hv[r][0], s, sh), 0.f);
        o0.y = fmaxf(fmaf((float)hv[r][1], s, sh), 0.f);
        o0.z = fmaxf(fmaf((float)hv[r][2], s, sh), 0.f);
        o0.w = fmaxf(fmaf((float)hv[r][3], s, sh), 0.f);
        o1.x = fmaxf(fmaf((float)hv[r][4], s, sh), 0.f);
        o1.y = fmaxf(fmaf((float)hv[r][5], s, sh), 0.f);
        o1.z = fmaxf(fmaf((float)hv[r][6], s, sh), 0.f);
        o1.w = fmaxf(fmaf((float)hv[r][7], s, sh), 0.f);
        float* rp = op + (row0 + r) * HW + col0;
        __builtin_nontemporal_store(o0, (f4v*)rp);
        __builtin_nontemporal_store(o1, (f4v*)(rp + 4));
    }
}

extern "C" void kernel_launch(void* const* d_in, const int* in_sizes, int n_in,
                              void* d_out, int out_size, void* d_ws, size_t ws_size,
                              hipStream_t stream) {
    const float* x     = (const float*)d_in[0];
    const float* w     = (const float*)d_in[1];
    const float* b     = (const float*)d_in[2];
    const float* gamma = (const float*)d_in[3];
    const float* beta  = (const float*)d_in[4];
    float* out = (float*)d_out;

    _Float16* yh  = (_Float16*)d_ws;
    float* parts  = (float*)d_ws + PART_OFF;
    pass_conv_stats<<<NB * NCH * NQ, 256, 0, stream>>>(x, w, b, yh, parts);
    pass_norm<<<NB * NCH, 256, 0, stream>>>(yh, parts, gamma, beta, out);
}

// Round 13
// 73.141 us; speedup vs baseline: 1.5737x; 1.5737x over previous
//
#include <hip/hip_runtime.h>

#define HW        128
#define PLANE     16384            // 128*128
#define NCH       64
#define NB        32
#define NQ        4                // quarter-planes (32 rows each)
#define NPART     8192             // NB*NCH*NQ partials per array
#define COUNT_INV (1.0f / 524288.0f)
#define EPSV      1e-5f

#define YELEMS    (NB * NCH * PLANE)            // 33,554,432
#define PART_OFF  (YELEMS / 2)                  // float index of partials in ws

typedef float    f4v __attribute__((ext_vector_type(4)));
typedef _Float16 h4v __attribute__((ext_vector_type(4)));

// ws layout:
//   bytes [0 .. 67108863]           y as fp16 (NCHW, same indexing as x)
//   floats[PART_OFF .. +8191]       per-quarter sum,   idx = c*128 + (n*4+q)
//   floats[PART_OFF+8192 .. +16383] per-quarter sumsq, same layout

__device__ __forceinline__ void load_win(const float* __restrict__ bp, int r0, int w4,
                                         bool hasL, bool hasR, float (&v)[6][6]) {
#pragma unroll
    for (int i = 0; i < 6; ++i) {
        int g = r0 - 1 + i;
        if ((unsigned)g < (unsigned)HW) {
            const float* rp = bp + g * HW + w4;
            float4 m = *(const float4*)rp;
            v[i][0] = hasL ? rp[-1] : 0.f;
            v[i][1] = m.x; v[i][2] = m.y; v[i][3] = m.z; v[i][4] = m.w;
            v[i][5] = hasR ? rp[4] : 0.f;
        } else {
#pragma unroll
            for (int j = 0; j < 6; ++j) v[i][j] = 0.f;
        }
    }
}

__device__ __forceinline__ void conv_row(const float (&tp)[6], const float (&md)[6],
                                         const float (&bt)[6], const float* W,
                                         float bias, float (&acc)[4]) {
#pragma unroll
    for (int j = 0; j < 4; ++j) {
        float a = bias;
        a = fmaf(tp[j],     W[0], a);
        a = fmaf(tp[j + 1], W[1], a);
        a = fmaf(tp[j + 2], W[2], a);
        a = fmaf(md[j],     W[3], a);
        a = fmaf(md[j + 1], W[4], a);
        a = fmaf(md[j + 2], W[5], a);
        a = fmaf(bt[j],     W[6], a);
        a = fmaf(bt[j + 1], W[7], a);
        a = fmaf(bt[j + 2], W[8], a);
        acc[j] = a;
    }
}

// ---------- pass 1: conv -> y(fp16) + per-quarter sum/sumsq ----------
__global__ __launch_bounds__(256) void pass_conv_stats(const float* __restrict__ x,
                                                       const float* __restrict__ wgt,
                                                       const float* __restrict__ bias,
                                                       _Float16* __restrict__ yh,
                                                       float* __restrict__ partials) {
    __shared__ float red[8];
    const int bid   = blockIdx.x;        // plane*4 + q
    const int q     = bid & 3;
    const int plane = bid >> 2;          // n*64 + c
    const int c     = plane & 63;
    const int n     = plane >> 6;
    const int t     = threadIdx.x;
    const int cg    = t & 31, rg = t >> 5;
    const int w4    = cg * 4, r0 = q * 32 + rg * 4;
    const bool hasL = (cg != 0), hasR = (cg != 31);

    float W[9];
#pragma unroll
    for (int k = 0; k < 9; ++k) W[k] = wgt[c * 9 + k];
    const float bv = bias[c];
    const float* bp = x + (size_t)plane * PLANE;
    _Float16* yp = yh + (size_t)plane * PLANE;

    float v[6][6];
    load_win(bp, r0, w4, hasL, hasR, v);

    float sum = 0.f, sq = 0.f;
#pragma unroll
    for (int k = 0; k < 4; ++k) {
        float acc[4];
        conv_row(v[k], v[k + 1], v[k + 2], W, bv, acc);
        h4v hv;
        hv.x = (_Float16)acc[0]; hv.y = (_Float16)acc[1];
        hv.z = (_Float16)acc[2]; hv.w = (_Float16)acc[3];
        *(h4v*)(yp + (r0 + k) * HW + w4) = hv;   // regular store: stays cached for pass 2
#pragma unroll
        for (int j = 0; j < 4; ++j) {
            sum += acc[j];
            sq = fmaf(acc[j], acc[j], sq);
        }
    }

#pragma unroll
    for (int off = 32; off; off >>= 1) {
        sum += __shfl_down(sum, off);
        sq  += __shfl_down(sq, off);
    }
    const int wave = t >> 6, lane = t & 63;
    if (lane == 0) { red[wave] = sum; red[4 + wave] = sq; }
    __syncthreads();
    if (t == 0) {
        const int pi = n * 4 + q;        // 0..127
        partials[c * 128 + pi]         = red[0] + red[1] + red[2] + red[3];
        partials[NPART + c * 128 + pi] = red[4] + red[5] + red[6] + red[7];
    }
}

// ---------- pass 2: elementwise normalize + relu from y(fp16) ----------
__global__ __launch_bounds__(256) void pass_norm(const _Float16* __restrict__ yh,
                                                 const float* __restrict__ partials,
                                                 const float* __restrict__ gamma,
                                                 const float* __restrict__ beta,
                                                 float* __restrict__ out) {
    const int bid   = blockIdx.x;        // plane*4 + q
    const int q     = bid & 3;
    const int plane = bid >> 2;
    const int c     = plane & 63;
    const int t     = threadIdx.x;
    const int cg    = t & 31, rg = t >> 5;
    const int w4    = cg * 4, r0 = q * 32 + rg * 4;

    const _Float16* yp = yh + (size_t)plane * PLANE;

    // issue the 4 y-loads up front (regular loads: y is L2/L3-hot from pass 1)
    h4v hv[4];
#pragma unroll
    for (int k = 0; k < 4; ++k)
        hv[k] = *(const h4v*)(yp + (r0 + k) * HW + w4);

    // wave-local stats fold: 128 partials per channel, coalesced, no LDS/barrier
    const int lane = t & 63;
    float S = partials[c * 128 + lane]         + partials[c * 128 + 64 + lane];
    float Q = partials[NPART + c * 128 + lane] + partials[NPART + c * 128 + 64 + lane];
#pragma unroll
    for (int off = 32; off; off >>= 1) {
        S += __shfl_xor(S, off);
        Q += __shfl_xor(Q, off);
    }
    const float mean = S * COUNT_INV;
    const float var  = fmaxf(Q * COUNT_INV - mean * mean, 0.f);
    const float s    = gamma[c] * rsqrtf(var + EPSV);
    const float sh   = beta[c] - mean * s;

    float* op = out + (size_t)plane * PLANE;
#pragma unroll
    for (int k = 0; k < 4; ++k) {
        f4v o;
        o.x = fmaxf(fmaf((float)hv[k].x, s, sh), 0.f);
        o.y = fmaxf(fmaf((float)hv[k].y, s, sh), 0.f);
        o.z = fmaxf(fmaf((float)hv[k].z, s, sh), 0.f);
        o.w = fmaxf(fmaf((float)hv[k].w, s, sh), 0.f);
        __builtin_nontemporal_store(o, (f4v*)(op + (r0 + k) * HW + w4));
    }
}

extern "C" void kernel_launch(void* const* d_in, const int* in_sizes, int n_in,
                              void* d_out, int out_size, void* d_ws, size_t ws_size,
                              hipStream_t stream) {
    const float* x     = (const float*)d_in[0];
    const float* w     = (const float*)d_in[1];
    const float* b     = (const float*)d_in[2];
    const float* gamma = (const float*)d_in[3];
    const float* beta  = (const float*)d_in[4];
    float* out = (float*)d_out;

    _Float16* yh  = (_Float16*)d_ws;
    float* parts  = (float*)d_ws + PART_OFF;
    pass_conv_stats<<<NB * NCH * NQ, 256, 0, stream>>>(x, w, b, yh, parts);
    pass_norm<<<NB * NCH * NQ, 256, 0, stream>>>(yh, parts, gamma, beta, out);
}